// Round 2
// baseline (690.117 us; speedup 1.0000x reference)
//
#include <hip/hip_runtime.h>

#define BATCH 8
#define CH 128
#define NPIX 65536
#define PN 1024   // path_num
// psq = 64, channel = 128

// ---------------- K0: precompute M = Wq^T Wk, wqbk = Wq^T bk, wkbq = Wk^T bq, c0 = bq.bk
__global__ __launch_bounds__(256) void k0_precompute(
    const float* __restrict__ Wq, const float* __restrict__ bq,
    const float* __restrict__ Wk, const float* __restrict__ bk,
    float* __restrict__ M, float* __restrict__ wqbk,
    float* __restrict__ wkbq, float* __restrict__ c0) {
  int t = blockIdx.x * 256 + threadIdx.x;
  if (t < 16384) {
    int c = t >> 7, c2 = t & 127;
    float s = 0.f;
    for (int o = 0; o < 128; ++o) s += Wq[o * 128 + c] * Wk[o * 128 + c2];
    M[t] = s;
  } else if (t < 16512) {
    int c = t - 16384;
    float s = 0.f;
    for (int o = 0; o < 128; ++o) s += Wq[o * 128 + c] * bk[o];
    wqbk[c] = s;
  } else if (t < 16640) {
    int c = t - 16512;
    float s = 0.f;
    for (int o = 0; o < 128; ++o) s += bq[o] * Wk[o * 128 + c];
    wkbq[c] = s;
  } else if (t == 16640) {
    float s = 0.f;
    for (int o = 0; o < 128; ++o) s += bq[o] * bk[o];
    c0[0] = s;
  }
}

// ---------------- K1: channel mean+max, scatter into Hilbert/feat layout
__global__ __launch_bounds__(256) void k1_reduce_permute(
    const float* __restrict__ x, const int* __restrict__ rehil,
    float* __restrict__ F) {
  const int b = blockIdx.y;
  const int t = blockIdx.x * 256 + threadIdx.x;  // 0..16383
  const int i0 = t * 4;
  const float* xb = x + (size_t)b * CH * NPIX + i0;
  float4 s = make_float4(0.f, 0.f, 0.f, 0.f);
  float4 m = make_float4(-1e30f, -1e30f, -1e30f, -1e30f);
  for (int c = 0; c < CH; ++c) {
    const float4 v = *(const float4*)(xb + (size_t)c * NPIX);
    s.x += v.x; s.y += v.y; s.z += v.z; s.w += v.w;
    m.x = fmaxf(m.x, v.x); m.y = fmaxf(m.y, v.y);
    m.z = fmaxf(m.z, v.z); m.w = fmaxf(m.w, v.w);
  }
  const float inv = 1.f / (float)CH;
  float mean[4] = {s.x * inv, s.y * inv, s.z * inv, s.w * inv};
  float mx[4] = {m.x, m.y, m.z, m.w};
  const int4 d4 = *(const int4*)(rehil + i0);
  int ds[4] = {d4.x, d4.y, d4.z, d4.w};
  float* Fb = F + (size_t)b * CH * PN;
#pragma unroll
  for (int e = 0; e < 4; ++e) {
    int d = ds[e];
    int p = d >> 6, j = d & 63;
    Fb[j * PN + p] = mean[e];
    Fb[(64 + j) * PN + p] = mx[e];
  }
}

// ---------------- KU: u[b][p] = F^T wqbk ; v[b][q] = F^T wkbq
__global__ __launch_bounds__(256) void ku_uv(
    const float* __restrict__ F, const float* __restrict__ wqbk,
    const float* __restrict__ wkbq, float* __restrict__ u, float* __restrict__ v) {
  const int b = blockIdx.y;
  const int p = blockIdx.x * 256 + threadIdx.x;  // 0..1023
  const float* Fb = F + (size_t)b * CH * PN;
  float su = 0.f, sv = 0.f;
  for (int c = 0; c < CH; ++c) {
    float f = Fb[c * PN + p];
    su = fmaf(f, wqbk[c], su);
    sv = fmaf(f, wkbq[c], sv);
  }
  u[b * PN + p] = su;
  v[b * PN + p] = sv;
}

// ---------------- K2: C = [M;Wv] * F (256x1024, K=128). rows<128 -> G; rows>=128 -> Vt (+bv)
__global__ __launch_bounds__(256) void k2_gv(
    const float* __restrict__ M, const float* __restrict__ Wv,
    const float* __restrict__ bv, const float* __restrict__ F,
    float* __restrict__ G, float* __restrict__ Vt) {
  __shared__ float As[16][64];
  __shared__ float Bs[16][64];
  const int b = blockIdx.z;
  const int r0 = blockIdx.y * 64;
  const int q0 = blockIdx.x * 64;
  const float* Fb = F + (size_t)b * CH * PN;
  const int t = threadIdx.x;
  const int tx = t & 15, ty = t >> 4;
  const int arow = t & 63, ak4 = (t >> 6) * 4;
  float acc[4][4] = {};
  for (int k0 = 0; k0 < 128; k0 += 16) {
    const int r = r0 + arow;
    const float* Arow = (r < 128) ? (M + r * 128) : (Wv + (r - 128) * 128);
    float4 a = *(const float4*)(Arow + k0 + ak4);
    As[ak4 + 0][arow] = a.x;
    As[ak4 + 1][arow] = a.y;
    As[ak4 + 2][arow] = a.z;
    As[ak4 + 3][arow] = a.w;
    *(float4*)&Bs[ty][tx * 4] =
        *(const float4*)(Fb + (size_t)(k0 + ty) * PN + q0 + tx * 4);
    __syncthreads();
#pragma unroll
    for (int kk = 0; kk < 16; ++kk) {
      float4 a4 = *(const float4*)&As[kk][ty * 4];
      float4 b4 = *(const float4*)&Bs[kk][tx * 4];
      float av[4] = {a4.x, a4.y, a4.z, a4.w};
      float bw[4] = {b4.x, b4.y, b4.z, b4.w};
#pragma unroll
      for (int i = 0; i < 4; ++i)
#pragma unroll
        for (int j = 0; j < 4; ++j) acc[i][j] = fmaf(av[i], bw[j], acc[i][j]);
    }
    __syncthreads();
  }
  float* Gb = G + (size_t)b * CH * PN;
  float* Vtb = Vt + (size_t)b * PN * CH;
#pragma unroll
  for (int i = 0; i < 4; ++i) {
    const int r = r0 + ty * 4 + i;
#pragma unroll
    for (int j = 0; j < 4; ++j) {
      const int q = q0 + tx * 4 + j;
      if (r < 128) Gb[r * PN + q] = acc[i][j];
      else Vtb[(size_t)q * CH + (r - 128)] = acc[i][j] + bv[r - 128];
    }
  }
}

// ---------------- K3: St[b][q][p] = G^T F + u[p] + v[q] + c0 ; 128x128 tile, 8x8 micro
__global__ __launch_bounds__(256) void k3_scores128(
    const float* __restrict__ G, const float* __restrict__ F,
    const float* __restrict__ u, const float* __restrict__ v,
    const float* __restrict__ c0, float* __restrict__ St) {
  __shared__ float As[16][128];  // G[k][q-tile]
  __shared__ float Bs[16][128];  // F[k][p-tile]
  const int b = blockIdx.z;
  const int q0 = blockIdx.y * 128;
  const int p0 = blockIdx.x * 128;
  const float* Gb = G + (size_t)b * CH * PN;
  const float* Fb = F + (size_t)b * CH * PN;
  const int t = threadIdx.x;
  const int tx = t & 15, ty = t >> 4;
  const int sr = t >> 4;          // staging row 0..15
  const int sc = (t & 15) * 8;    // staging col
  float acc[8][8] = {};
  for (int k0 = 0; k0 < 128; k0 += 16) {
    const float* gsrc = Gb + (size_t)(k0 + sr) * PN + q0 + sc;
    const float* fsrc = Fb + (size_t)(k0 + sr) * PN + p0 + sc;
    *(float4*)&As[sr][sc] = *(const float4*)gsrc;
    *(float4*)&As[sr][sc + 4] = *(const float4*)(gsrc + 4);
    *(float4*)&Bs[sr][sc] = *(const float4*)fsrc;
    *(float4*)&Bs[sr][sc + 4] = *(const float4*)(fsrc + 4);
    __syncthreads();
#pragma unroll
    for (int kk = 0; kk < 16; ++kk) {
      float a0[8], b0[8];
      *(float4*)&a0[0] = *(const float4*)&As[kk][ty * 4];
      *(float4*)&a0[4] = *(const float4*)&As[kk][64 + ty * 4];
      *(float4*)&b0[0] = *(const float4*)&Bs[kk][tx * 4];
      *(float4*)&b0[4] = *(const float4*)&Bs[kk][64 + tx * 4];
#pragma unroll
      for (int i = 0; i < 8; ++i)
#pragma unroll
        for (int j = 0; j < 8; ++j) acc[i][j] = fmaf(a0[i], b0[j], acc[i][j]);
    }
    __syncthreads();
  }
  const float cc = c0[0];
  float* Sb = St + (size_t)b * PN * PN;
  const float* ub = u + b * PN;
  const float* vb = v + b * PN;
  float4 u0 = *(const float4*)(ub + p0 + tx * 4);
  float4 u1 = *(const float4*)(ub + p0 + 64 + tx * 4);
  float ua[8] = {u0.x, u0.y, u0.z, u0.w, u1.x, u1.y, u1.z, u1.w};
#pragma unroll
  for (int i = 0; i < 8; ++i) {
    const int q = q0 + ((i < 4) ? (ty * 4 + i) : (64 + ty * 4 + i - 4));
    const float vq = vb[q] + cc;
    float* row = Sb + (size_t)q * PN;
#pragma unroll
    for (int jh = 0; jh < 2; ++jh) {
      float4 o;
      o.x = acc[i][jh * 4 + 0] + ua[jh * 4 + 0] + vq;
      o.y = acc[i][jh * 4 + 1] + ua[jh * 4 + 1] + vq;
      o.z = acc[i][jh * 4 + 2] + ua[jh * 4 + 2] + vq;
      o.w = acc[i][jh * 4 + 3] + ua[jh * 4 + 3] + vq;
      *(float4*)(row + p0 + jh * 64 + tx * 4) = o;
    }
  }
}

// ---------------- K4: per (b,q) row: m = max_p, invZ = 1/sum_p exp(s-m)
__global__ __launch_bounds__(256) void k4_softmax_stats(
    const float* __restrict__ St, float* __restrict__ mOut,
    float* __restrict__ izOut) {
  const int wid = threadIdx.x >> 6;
  const int lane = threadIdx.x & 63;
  const int row = blockIdx.x * 4 + wid;  // b*1024+q
  const float* Sr = St + (size_t)row * PN;
  float4 r[4];
  float m = -1e30f;
#pragma unroll
  for (int ch = 0; ch < 4; ++ch) {
    r[ch] = *(const float4*)(Sr + ch * 256 + lane * 4);
    m = fmaxf(m, fmaxf(fmaxf(r[ch].x, r[ch].y), fmaxf(r[ch].z, r[ch].w)));
  }
#pragma unroll
  for (int off = 32; off >= 1; off >>= 1) m = fmaxf(m, __shfl_xor(m, off));
  float z = 0.f;
#pragma unroll
  for (int ch = 0; ch < 4; ++ch) {
    z += __expf(r[ch].x - m) + __expf(r[ch].y - m) +
         __expf(r[ch].z - m) + __expf(r[ch].w - m);
  }
#pragma unroll
  for (int off = 32; off >= 1; off >>= 1) z += __shfl_xor(z, off);
  if (lane == 0) {
    mOut[row] = m;
    izOut[row] = 1.f / z;
  }
}

// ---------------- K5: partial x3c over q-chunk of 128; 128(c)x128(p) tile, 8x8 micro
__global__ __launch_bounds__(256) void k5_av128(
    const float* __restrict__ Vt, const float* __restrict__ St,
    const float* __restrict__ mIn, const float* __restrict__ izIn,
    float* __restrict__ P) {
  __shared__ float As[16][128];  // Vt[q][c]
  __shared__ float Bs[16][128];  // E[q][p-tile]
  const int b = blockIdx.z;
  const int part = blockIdx.y;       // 0..7, q-chunk of 128
  const int p0 = blockIdx.x * 128;
  const float* Vtb = Vt + (size_t)b * PN * CH;
  const float* Sb = St + (size_t)b * PN * PN;
  const float* mb = mIn + b * PN;
  const float* izb = izIn + b * PN;
  const int t = threadIdx.x;
  const int tx = t & 15, ty = t >> 4;
  const int sr = t >> 4;
  const int sc = (t & 15) * 8;
  float acc[8][8] = {};
  const int qbase = part * 128;
  for (int k0 = 0; k0 < 128; k0 += 16) {
    const int q = qbase + k0 + sr;
    const float* asrc = Vtb + (size_t)q * CH + sc;
    *(float4*)&As[sr][sc] = *(const float4*)asrc;
    *(float4*)&As[sr][sc + 4] = *(const float4*)(asrc + 4);
    const float mq = mb[q];
    const float iz = izb[q];
    const float* ssrc = Sb + (size_t)q * PN + p0 + sc;
    float4 s0 = *(const float4*)ssrc;
    float4 s1 = *(const float4*)(ssrc + 4);
    float4 e0, e1;
    e0.x = __expf(s0.x - mq) * iz; e0.y = __expf(s0.y - mq) * iz;
    e0.z = __expf(s0.z - mq) * iz; e0.w = __expf(s0.w - mq) * iz;
    e1.x = __expf(s1.x - mq) * iz; e1.y = __expf(s1.y - mq) * iz;
    e1.z = __expf(s1.z - mq) * iz; e1.w = __expf(s1.w - mq) * iz;
    *(float4*)&Bs[sr][sc] = e0;
    *(float4*)&Bs[sr][sc + 4] = e1;
    __syncthreads();
#pragma unroll
    for (int kk = 0; kk < 16; ++kk) {
      float a0[8], b0[8];
      *(float4*)&a0[0] = *(const float4*)&As[kk][ty * 4];
      *(float4*)&a0[4] = *(const float4*)&As[kk][64 + ty * 4];
      *(float4*)&b0[0] = *(const float4*)&Bs[kk][tx * 4];
      *(float4*)&b0[4] = *(const float4*)&Bs[kk][64 + tx * 4];
#pragma unroll
      for (int i = 0; i < 8; ++i)
#pragma unroll
        for (int j = 0; j < 8; ++j) acc[i][j] = fmaf(a0[i], b0[j], acc[i][j]);
    }
    __syncthreads();
  }
  // store partial: P[((part*BATCH + b)*CH + c)*PN + p]
  float* Pb = P + ((size_t)(part * BATCH + b) * CH) * PN;
#pragma unroll
  for (int i = 0; i < 8; ++i) {
    const int c = (i < 4) ? (ty * 4 + i) : (64 + ty * 4 + i - 4);
    float* row = Pb + (size_t)c * PN;
#pragma unroll
    for (int jh = 0; jh < 2; ++jh) {
      float4 o;
      o.x = acc[i][jh * 4 + 0];
      o.y = acc[i][jh * 4 + 1];
      o.z = acc[i][jh * 4 + 2];
      o.w = acc[i][jh * 4 + 3];
      *(float4*)(row + p0 + jh * 64 + tx * 4) = o;
    }
  }
}

// ---------------- K6: reduce 8 partials -> X3
__global__ __launch_bounds__(256) void k6_reduce(
    const float* __restrict__ P, float* __restrict__ X3) {
  const size_t t = (size_t)blockIdx.x * 256 + threadIdx.x;  // 0..262143
  const size_t idx = t * 4;
  const size_t stride = (size_t)BATCH * CH * PN;  // 1M floats per part
  float4 s = *(const float4*)(P + idx);
#pragma unroll
  for (int part = 1; part < 8; ++part) {
    const float4 v = *(const float4*)(P + part * stride + idx);
    s.x += v.x; s.y += v.y; s.z += v.z; s.w += v.w;
  }
  *(float4*)(X3 + idx) = s;
}

// ---------------- K6g: gate[b][i] = sigmoid(w0*x3c[j][p] + w1*x3c[64+j][p] + bpre)
__global__ __launch_bounds__(256) void k6g_gate(
    const float* __restrict__ X3, const int* __restrict__ rehil,
    const float* __restrict__ Wpre, const float* __restrict__ bpre,
    float* __restrict__ gate) {
  const int b = blockIdx.y;
  const int t = blockIdx.x * 256 + threadIdx.x;  // 0..16383
  const int i0 = t * 4;
  const float w0 = Wpre[0], w1 = Wpre[1], b0 = bpre[0];
  const int4 d4 = *(const int4*)(rehil + i0);
  const float* X3b = X3 + (size_t)b * CH * PN;
  int ds[4] = {d4.x, d4.y, d4.z, d4.w};
  float4 g;
  float* gp = &g.x;
#pragma unroll
  for (int e = 0; e < 4; ++e) {
    const int d = ds[e];
    const int p = d >> 6, j = d & 63;
    const float r0v = X3b[j * PN + p];
    const float r1v = X3b[(64 + j) * PN + p];
    const float logit = fmaf(w0, r0v, fmaf(w1, r1v, b0));
    gp[e] = 1.f / (1.f + __expf(-logit));
  }
  *(float4*)(gate + (size_t)b * NPIX + i0) = g;
}

// ---------------- K7: out = gate * x (pure stream)
__global__ __launch_bounds__(256) void k7_out(
    const float* __restrict__ x, const float* __restrict__ gate,
    float* __restrict__ out) {
  const int b = blockIdx.y;
  const int t = blockIdx.x * 256 + threadIdx.x;  // 0..16383
  const int i0 = t * 4;
  const float4 g = *(const float4*)(gate + (size_t)b * NPIX + i0);
  const size_t base = (size_t)b * CH * NPIX + i0;
#pragma unroll 4
  for (int c = 0; c < CH; ++c) {
    const float4 v = *(const float4*)(x + base + (size_t)c * NPIX);
    float4 o;
    o.x = v.x * g.x;
    o.y = v.y * g.y;
    o.z = v.z * g.z;
    o.w = v.w * g.w;
    *(float4*)(out + base + (size_t)c * NPIX) = o;
  }
}

extern "C" void kernel_launch(void* const* d_in, const int* in_sizes, int n_in,
                              void* d_out, int out_size, void* d_ws,
                              size_t ws_size, hipStream_t stream) {
  const float* x = (const float*)d_in[0];
  const float* Wq = (const float*)d_in[1];
  const float* bq = (const float*)d_in[2];
  const float* Wk = (const float*)d_in[3];
  const float* bk = (const float*)d_in[4];
  const float* Wv = (const float*)d_in[5];
  const float* bv = (const float*)d_in[6];
  const float* Wpre = (const float*)d_in[7];
  const float* bpre = (const float*)d_in[8];
  const int* rehil = (const int*)d_in[10];
  float* out = (float*)d_out;
  float* ws = (float*)d_ws;

  // workspace layout (floats)
  const size_t SZ_FEAT = (size_t)BATCH * CH * PN;  // 1,048,576
  float* F = ws;
  float* G = F + SZ_FEAT;
  float* Vt = G + SZ_FEAT;
  float* X3 = Vt + SZ_FEAT;
  float* Mw = X3 + SZ_FEAT;           // 16384
  float* wqbk = Mw + 16384;           // 128
  float* wkbq = wqbk + 128;           // 128
  float* c0w = wkbq + 128;            // 1 (pad 64)
  float* uw = c0w + 64;               // 8192
  float* vw = uw + 8192;              // 8192
  float* mw = vw + 8192;              // 8192
  float* izw = mw + 8192;             // 8192
  float* gatew = izw + 8192;          // 524288
  float* Pw = gatew + 524288;         // 8 * 1M = 8,388,608
  float* Stw = Pw + 8 * SZ_FEAT;      // 8,388,608
  const size_t need = (size_t)(Stw - ws) + (size_t)BATCH * PN * PN;
  float* St = Stw;
  if (ws_size < need * sizeof(float)) {
    // fall back: score matrix lives in d_out (same byte size); it is fully
    // consumed by k5 before k7 overwrites d_out with the real output.
    St = out;
  }

  k0_precompute<<<66, 256, 0, stream>>>(Wq, bq, Wk, bk, Mw, wqbk, wkbq, c0w);
  k1_reduce_permute<<<dim3(64, BATCH), 256, 0, stream>>>(x, rehil, F);
  ku_uv<<<dim3(4, BATCH), 256, 0, stream>>>(F, wqbk, wkbq, uw, vw);
  k2_gv<<<dim3(16, 4, BATCH), 256, 0, stream>>>(Mw, Wv, bv, F, G, Vt);
  k3_scores128<<<dim3(8, 8, BATCH), 256, 0, stream>>>(G, F, uw, vw, c0w, St);
  k4_softmax_stats<<<2048, 256, 0, stream>>>(St, mw, izw);
  k5_av128<<<dim3(8, 8, BATCH), 256, 0, stream>>>(Vt, St, mw, izw, Pw);
  k6_reduce<<<1024, 256, 0, stream>>>(Pw, X3);
  k6g_gate<<<dim3(64, BATCH), 256, 0, stream>>>(X3, rehil, Wpre, bpre, gatew);
  k7_out<<<dim3(64, BATCH), 256, 0, stream>>>(x, gatew, out);
}